// Round 1
// baseline (2209.701 us; speedup 1.0000x reference)
//
#include <hip/hip_runtime.h>
#include <math.h>

// Problem constants (b=2, dim=48, heads=8, H=W=256)
#define HW_ 65536
#define NB 2

__device__ __forceinline__ float wave_reduce_sum(float v) {
    #pragma unroll
    for (int off = 32; off; off >>= 1) v += __shfl_down(v, off, 64);
    return v;
}

// ---------------------------------------------------------------------------
// 1x1 conv: out[b, oc0+o, p] = (res?) + sum_c wgt[(oc0+o)*wRS + c] * in[b, c, p]
// Each thread owns one spatial position p, accumulates OC outputs in registers.
// Weights staged in LDS. Requires Cin % 4 == 0, Cin <= 96, HW_ % 256 == 0.
// ---------------------------------------------------------------------------
template <int OC>
__global__ __launch_bounds__(256) void conv1x1_k(
    const float* __restrict__ in, long inBS,
    const float* __restrict__ wgt, int wRS,
    const float* __restrict__ res, long resBS,
    float* __restrict__ out, long outBS,
    int Cin, int accumulate)
{
    __shared__ __align__(16) float wl[OC * 96];
    const int tid = threadIdx.x;
    const int oc0 = blockIdx.z * OC;
    for (int idx = tid; idx < OC * Cin; idx += 256) {
        int o = idx / Cin, c = idx - o * Cin;
        wl[idx] = wgt[(long)(oc0 + o) * wRS + c];
    }
    __syncthreads();

    const long p = (long)blockIdx.x * 256 + tid;
    const int b = blockIdx.y;
    const float* inp = in + (long)b * inBS + p;

    float acc[OC];
    #pragma unroll
    for (int o = 0; o < OC; o++) acc[o] = 0.f;

    for (int c0 = 0; c0 < Cin; c0 += 4) {
        float x0 = inp[(long)c0 * HW_];
        float x1 = inp[(long)(c0 + 1) * HW_];
        float x2 = inp[(long)(c0 + 2) * HW_];
        float x3 = inp[(long)(c0 + 3) * HW_];
        #pragma unroll
        for (int o = 0; o < OC; o++) {
            const float4 wv = *(const float4*)&wl[o * Cin + c0];
            acc[o] = fmaf(wv.x, x0, fmaf(wv.y, x1, fmaf(wv.z, x2, fmaf(wv.w, x3, acc[o]))));
        }
    }

    float* op = out + (long)b * outBS + (long)oc0 * HW_ + p;
    if (res) {
        const float* rp = res + (long)b * resBS + (long)oc0 * HW_ + p;
        #pragma unroll
        for (int o = 0; o < OC; o++) op[(long)o * HW_] = rp[(long)o * HW_] + acc[o];
    } else if (accumulate) {
        #pragma unroll
        for (int o = 0; o < OC; o++) op[(long)o * HW_] += acc[o];
    } else {
        #pragma unroll
        for (int o = 0; o < OC; o++) op[(long)o * HW_] = acc[o];
    }
}

// ---------------------------------------------------------------------------
// depthwise 3x3, pad=1, H=W=256. weight row = wOff + blockIdx.y.
// ---------------------------------------------------------------------------
__global__ __launch_bounds__(256) void dw3x3_k(
    const float* __restrict__ in, float* __restrict__ out,
    const float* __restrict__ w, int wOff, int C)
{
    const long p = (long)blockIdx.x * 256 + threadIdx.x;
    const int c = blockIdx.y, b = blockIdx.z;
    const long base = ((long)b * C + c) * HW_;
    const int y = (int)(p >> 8), x = (int)(p & 255);
    const float* wp = w + (long)(wOff + c) * 9;
    const float* ip = in + base;
    float acc = 0.f;
    #pragma unroll
    for (int dy = -1; dy <= 1; dy++) {
        int yy = y + dy;
        if ((unsigned)yy >= 256u) continue;
        #pragma unroll
        for (int dx = -1; dx <= 1; dx++) {
            int xx = x + dx;
            if ((unsigned)xx >= 256u) continue;
            acc = fmaf(wp[(dy + 1) * 3 + (dx + 1)], ip[yy * 256 + xx], acc);
        }
    }
    out[base + p] = acc;
}

// ---------------------------------------------------------------------------
// L2 norms of q,k channels (ch 0..95) of Q1 and Q2. nrm[t*192 + b*96 + ch].
// ---------------------------------------------------------------------------
__global__ __launch_bounds__(256) void norms_k(
    const float* __restrict__ Q1, const float* __restrict__ Q2,
    float* __restrict__ nrm)
{
    const int row = blockIdx.x; // 0..383
    const int t = row / 192, rem = row % 192, b = rem / 96, ch = rem % 96;
    const float* src = (t ? Q2 : Q1) + ((long)b * 144 + ch) * HW_;
    float s = 0.f;
    for (int i = threadIdx.x; i < HW_; i += 256) { float v = src[i]; s = fmaf(v, v, s); }
    s = wave_reduce_sum(s);
    __shared__ float tmp[4];
    const int lane = threadIdx.x & 63, wid = threadIdx.x >> 6;
    if (!lane) tmp[wid] = s;
    __syncthreads();
    if (!threadIdx.x) nrm[row] = sqrtf(tmp[0] + tmp[1] + tmp[2] + tmp[3]);
}

// ---------------------------------------------------------------------------
// attn[a][b][h][c][d] = t_a[h] * <q,k_d> / (max(|q|,eps)*max(|k_d|,eps))
// a=0: q from Q2, k from Q1 (attn1). a=1: q from Q1, k from Q2 (attn2).
// One block per (a,b,h,c): 192 blocks.
// ---------------------------------------------------------------------------
__global__ __launch_bounds__(256) void attn_k(
    const float* __restrict__ Q1, const float* __restrict__ Q2,
    const float* __restrict__ nrm, const float* __restrict__ t1,
    const float* __restrict__ t2, float* __restrict__ att)
{
    const int id = blockIdx.x;
    const int a = id / 96, rem = id % 96, b = rem / 48, hc = rem % 48, h = hc / 6;
    const float* Qq = a ? Q1 : Q2;
    const float* Qk = a ? Q2 : Q1;
    const float* qp = Qq + ((long)b * 144 + hc) * HW_;
    const float* kp = Qk + ((long)b * 144 + 48 + h * 6) * HW_;

    float acc[6] = {0, 0, 0, 0, 0, 0};
    for (int i = threadIdx.x; i < HW_; i += 256) {
        float qv = qp[i];
        #pragma unroll
        for (int d = 0; d < 6; d++) acc[d] = fmaf(qv, kp[(long)d * HW_ + i], acc[d]);
    }
    __shared__ float red[4][6];
    const int lane = threadIdx.x & 63, wid = threadIdx.x >> 6;
    #pragma unroll
    for (int d = 0; d < 6; d++) {
        float v = wave_reduce_sum(acc[d]);
        if (!lane) red[wid][d] = v;
    }
    __syncthreads();
    if (!threadIdx.x) {
        const int qt = a ? 0 : 1; // tensor holding q (0=Q1, 1=Q2)
        const int kt = a ? 1 : 0;
        float qn = fmaxf(nrm[qt * 192 + b * 96 + hc], 1e-12f);
        float tv = a ? t2[h] : t1[h];
        #pragma unroll
        for (int d = 0; d < 6; d++) {
            float kn = fmaxf(nrm[kt * 192 + b * 96 + 48 + h * 6 + d], 1e-12f);
            float s = red[0][d] + red[1][d] + red[2][d] + red[3][d];
            att[(size_t)((a * 2 + b) * 8 + h) * 36 + (hc % 6) * 6 + d] = tv * s / (qn * kn);
        }
    }
}

// softmax over last dim (6) of attn, in place. 192 rows, 1 block of 192 threads.
__global__ void softmax6_k(float* __restrict__ att)
{
    float* a = att + threadIdx.x * 6;
    float m = a[0];
    #pragma unroll
    for (int i = 1; i < 6; i++) m = fmaxf(m, a[i]);
    float e[6], s = 0.f;
    #pragma unroll
    for (int i = 0; i < 6; i++) { e[i] = expf(a[i] - m); s += e[i]; }
    float inv = 1.f / s;
    #pragma unroll
    for (int i = 0; i < 6; i++) a[i] = e[i] * inv;
}

// out[b, hc, p] = sum_d att[b,h,c,d] * V[b, 96+h*6+d, p]   (V inside Qv base)
__global__ __launch_bounds__(256) void attnout_k(
    const float* __restrict__ Qv, const float* __restrict__ att,
    float* __restrict__ out)
{
    const long p = (long)blockIdx.x * 256 + threadIdx.x;
    const int hc = blockIdx.y, b = blockIdx.z, h = hc / 6, c = hc % 6;
    const float* ap = att + ((size_t)(b * 8 + h) * 36 + c * 6);
    const float* vp = Qv + ((long)b * 144 + 96 + h * 6) * HW_ + p;
    float acc = 0.f;
    #pragma unroll
    for (int d = 0; d < 6; d++) acc = fmaf(ap[d], vp[(long)d * HW_], acc);
    out[((long)b * 48 + hc) * HW_ + p] = acc;
}

// g = gelu_exact(g) * h, elementwise over 12,582,912 elements
__global__ __launch_bounds__(256) void gelumul_k(
    float* __restrict__ g, const float* __restrict__ h)
{
    const long i = (long)blockIdx.x * 256 + threadIdx.x;
    float x = g[i];
    float v = 0.5f * x * (1.f + erff(x * 0.70710678118654752440f));
    g[i] = v * h[i];
}

// out += acc elementwise
__global__ __launch_bounds__(256) void finaladd_k(
    float* __restrict__ out, const float* __restrict__ acc)
{
    const long i = (long)blockIdx.x * 256 + threadIdx.x;
    out[i] += acc[i];
}

extern "C" void kernel_launch(void* const* d_in, const int* in_sizes, int n_in,
                              void* d_out, int out_size, void* d_ws, size_t ws_size,
                              hipStream_t stream) {
    const float* x1      = (const float*)d_in[0];
    const float* x2      = (const float*)d_in[1];
    const float* t1      = (const float*)d_in[2];
    const float* t2      = (const float*)d_in[3];
    const float* qkv1_w  = (const float*)d_in[4];
    const float* qkv1_dw = (const float*)d_in[5];
    const float* qkv2_w  = (const float*)d_in[6];
    const float* qkv2_dw = (const float*)d_in[7];
    const float* mid1_w  = (const float*)d_in[8];
    const float* mid2_w  = (const float*)d_in[9];
    const float* pE_w    = (const float*)d_in[10];
    const float* pE_dw   = (const float*)d_in[11];
    const float* pE1_w   = (const float*)d_in[12];
    const float* pE1_dw  = (const float*)d_in[13];
    const float* pE2_w   = (const float*)d_in[14];
    const float* pE2_dw  = (const float*)d_in[15];
    const float* po1_w   = (const float*)d_in[16];
    const float* po2_w   = (const float*)d_in[17];
    float* dout = (float*)d_out;
    float* ws = (float*)d_ws;

    // workspace layout (floats); peak = 3*18,874,368 + stats ~= 226.5 MB
    const long SZ144 = (long)NB * 144 * HW_; // 18,874,368
    const long SZ96  = (long)NB * 96 * HW_;  // 12,582,912
    const long SZ48  = (long)NB * 48 * HW_;  //  6,291,456
    float* T0 = ws;              // qkv conv1x1 scratch (phase 1)
    float* Q1 = ws + SZ144;      // dw(qkv1)
    float* Q2 = ws + 2 * SZ144;  // dw(qkv2)
    float* O1 = ws;              // attn out 1 (reuses T0)
    float* O2 = ws + SZ48;       // attn out 2
    float* Ba = ws;              // phase-5 rotation buffers
    float* Bb = ws + SZ96;
    float* Bc = ws + 2 * SZ96;
    float* ACC = ws + 2 * SZ144; // po accumulator (reuses Q2 region)
    float* NRM = ws + 3 * SZ144; // 384 floats
    float* ATT = NRM + 384;      // 1152 floats

    const dim3 blk(256);
    const long BS48 = 48L * HW_, BS96 = 96L * HW_, BS144 = 144L * HW_;

    // --- phase 1: qkv = dw3x3(conv1x1(x)) for both branches
    conv1x1_k<72><<<dim3(256, NB, 2), blk, 0, stream>>>(x1, BS48, qkv1_w, 48, nullptr, 0, T0, BS144, 48, 0);
    dw3x3_k<<<dim3(256, 144, NB), blk, 0, stream>>>(T0, Q1, qkv1_dw, 0, 144);
    conv1x1_k<72><<<dim3(256, NB, 2), blk, 0, stream>>>(x2, BS48, qkv2_w, 48, nullptr, 0, T0, BS144, 48, 0);
    dw3x3_k<<<dim3(256, 144, NB), blk, 0, stream>>>(T0, Q2, qkv2_dw, 0, 144);

    // --- phase 2: norms, attention matrices, softmax
    norms_k<<<dim3(384), blk, 0, stream>>>(Q1, Q2, NRM);
    attn_k<<<dim3(192), blk, 0, stream>>>(Q1, Q2, NRM, t1, t2, ATT);
    softmax6_k<<<dim3(1), dim3(192), 0, stream>>>(ATT);

    // --- phase 3: out1 = softmax(attn1) @ v1, out2 = softmax(attn2) @ v2
    attnout_k<<<dim3(256, 48, NB), blk, 0, stream>>>(Q1, ATT, O1);
    attnout_k<<<dim3(256, 48, NB), blk, 0, stream>>>(Q2, ATT + 576, O2);

    // --- phase 4: x1n = x1 + mid1(out1) -> dout ch 0..47 ; x2n -> ch 48..95
    conv1x1_k<48><<<dim3(256, NB, 1), blk, 0, stream>>>(O1, BS48, mid1_w, 48, x1, BS48, dout, BS96, 48, 0);
    conv1x1_k<48><<<dim3(256, NB, 1), blk, 0, stream>>>(O2, BS48, mid2_w, 48, x2, BS48, dout + BS48, BS96, 48, 0);

    // --- phase 5: gated FFN tail, 4 chunks of 96 channels
    for (int i = 0; i < 4; i++) {
        // g chunk: conv1x1(dout 96ch -> 96ch) then dw3x3
        conv1x1_k<96><<<dim3(256, NB, 1), blk, 0, stream>>>(
            dout, BS96, pE_w + (size_t)i * 96 * 96, 96, nullptr, 0, Ba, BS96, 96, 0);
        dw3x3_k<<<dim3(256, 96, NB), blk, 0, stream>>>(Ba, Bb, pE_dw, i * 96, 96);
        // h chunk: conv1x1(x{1,2}n 48ch -> 96ch) then dw3x3
        const float* pek_w = (i < 2 ? pE1_w : pE2_w) + (size_t)(i & 1) * 96 * 48;
        conv1x1_k<96><<<dim3(256, NB, 1), blk, 0, stream>>>(
            dout + (i < 2 ? 0 : BS48), BS96, pek_w, 48, nullptr, 0, Bc, BS96, 48, 0);
        const float* pek_dw = (i < 2 ? pE1_dw : pE2_dw);
        dw3x3_k<<<dim3(256, 96, NB), blk, 0, stream>>>(Bc, Ba, pek_dw, (i & 1) * 96, 96);
        // X = gelu(g) * h  (into Bb)
        gelumul_k<<<dim3(49152), blk, 0, stream>>>(Bb, Ba);
        // ACC (+)= po @ X  (chunk of 96 input channels; col offset (i&1)*96)
        const float* pow_ = (i < 2 ? po1_w : po2_w) + (size_t)(i & 1) * 96;
        conv1x1_k<96><<<dim3(256, NB, 1), blk, 0, stream>>>(
            Bb, BS96, pow_, 192, nullptr, 0, ACC, BS96, 96, i ? 1 : 0);
    }

    // --- final: dout += ACC
    finaladd_k<<<dim3(49152), blk, 0, stream>>>(dout, ACC);
}